// Round 7
// baseline (1815.384 us; speedup 1.0000x reference)
//
#include <hip/hip_runtime.h>

// x:              [B, C, N_OUT]  f32   (512 planes x 65536)
// idx_mask:       [B, C, N_OUT]  i32 in [0, K)
// sample_map:     [N_OUT, K, P]  i32 in [0, N_IN)
// interp_weights: [N_OUT, K, P]  f32
// out:            [B, C, N_IN]   f32
#define BB      8
#define CC      64
#define N_OUT   65536
#define N_IN    262144
#define KK      9
#define PP      4
#define NE      (N_OUT * KK * PP)   // 2,359,296
#define NPLANES 512
#define CHUNK   32                  // n per gather block
#define NCHUNKS (N_IN / CHUNK)      // 8192
#define GTH     512                 // gather threads (8 waves)
#define NW      (GTH / 64)
#define NFB     64                  // fill/hist blocks
#define EPB     (NE / NFB)          // 36864 entries per build block

// ---------------- d_ws layout (int units) ----------------
// offsets [8193] (+pad)  bucket bases
// priv    [NFB][8192]    per-build-block histogram / base slices
// hdr     [N_OUT*9] u32 = start | (cnt<<16) per (o,k) into xk row
// entries int4[NE]       {(o<<5)|nl, w_bits, start|(cnt<<16), 0}
// xk      u32[N_OUT*512] per o: planes k-sorted, (x_bits & ~511) | plane_id
#define WS_OFFSETS 0
#define WS_PRIV    8208
#define WS_HDR     (8208 + NFB * 8192)            // 532496
#define WS_ENTR    (532496 + N_OUT * KK)          // 1122320 (16B aligned)
#define WS_XK      (1122320 + 4 * NE)             // 10559504
#define WS_END     (10559504 + N_OUT * 512)       // 44113936 ints (~168 MiB)

// ============================================================================
// k_xk: per o, sort the 512 planes' x by their idx_mask tap k.
//   xk[o][j] (j in k-sorted order) = (x_bits & 0xFFFFFE00) | plane_id (9 bits)
//   hdr[o*9+k] = start | (cnt << 16)
// ============================================================================
#define XKTILE 16
#define XPAD   520
__global__ __launch_bounds__(256) void k_xk(const float* __restrict__ x,
                                            const int*   __restrict__ idx,
                                            unsigned* __restrict__ xk,
                                            unsigned* __restrict__ hdr) {
    __shared__ float xs[XKTILE * XPAD];          // 33.3 KB [oo][p] padded
    __shared__ unsigned char ks[XKTILE * XPAD];  // 8.3 KB
    __shared__ unsigned ot[XKTILE * 512];        // 32 KB out tile
    __shared__ int cnt[XKTILE][12];
    __shared__ int cur[XKTILE][12];
    const int t = threadIdx.x;
    const int obase = blockIdx.x * XKTILE;

    for (int i = t; i < XKTILE * 12; i += 256) cnt[i / 12][i % 12] = 0;

    for (int i = t; i < 512 * (XKTILE / 4); i += 256) {   // 2048
        int p = i >> 2, q = i & 3;
        const size_t g = (size_t)p * N_OUT + obase + 4 * q;
        float4 xv = *(const float4*)(x + g);
        int4   kv = *(const int4*)(idx + g);
        int b = (4 * q) * XPAD + p;
        xs[b] = xv.x; xs[b + XPAD] = xv.y; xs[b + 2 * XPAD] = xv.z; xs[b + 3 * XPAD] = xv.w;
        ks[b] = (unsigned char)kv.x; ks[b + XPAD] = (unsigned char)kv.y;
        ks[b + 2 * XPAD] = (unsigned char)kv.z; ks[b + 3 * XPAD] = (unsigned char)kv.w;
    }
    __syncthreads();
    for (int i = t; i < XKTILE * 512; i += 256) {
        int oo = i >> 9, p = i & 511;
        atomicAdd(&cnt[oo][ks[oo * XPAD + p]], 1);
    }
    __syncthreads();
    if (t < XKTILE) {
        int s = 0;
        for (int k = 0; k < KK; ++k) {
            int c = cnt[t][k];
            cur[t][k] = s;
            hdr[(size_t)(obase + t) * KK + k] = (unsigned)(s | (c << 16));
            s += c;
        }
    }
    __syncthreads();
    for (int i = t; i < XKTILE * 512; i += 256) {
        int oo = i >> 9, p = i & 511;
        int k = ks[oo * XPAD + p];
        int pos = atomicAdd(&cur[oo][k], 1);
        unsigned xb = __float_as_uint(xs[oo * XPAD + p]);
        ot[(oo << 9) + pos] = (xb & 0xFFFFFE00u) | (unsigned)p;
    }
    __syncthreads();
    for (int i = t; i < XKTILE * 128; i += 256) {
        int oo = i >> 7, c4 = i & 127;
        ((int4*)(xk + (((size_t)(obase + oo)) << 9)))[c4] = ((const int4*)(ot + (oo << 9)))[c4];
    }
}

// ============================================================================
// Build phase: deterministic 3-phase counting sort, no global atomics.
// ============================================================================
__global__ __launch_bounds__(1024) void k_histA(const int* __restrict__ smap,
                                                int* __restrict__ priv) {
    __shared__ int h[8192];
    const int b = blockIdx.x;
    const int t = threadIdx.x;
    for (int i = t; i < 8192; i += 1024) h[i] = 0;
    __syncthreads();
    const int e0 = b * EPB;
    #pragma unroll 4
    for (int i = 0; i < EPB / 1024; ++i)
        atomicAdd(&h[smap[e0 + i * 1024 + t] >> 5], 1);
    __syncthreads();
    for (int i = t; i < 8192; i += 1024) priv[b * 8192 + i] = h[i];
}

// single block: column-wise (per key) exclusive scan over build blocks, then
// cross-key exclusive scan; priv becomes per-(block,key) global base.
__global__ __launch_bounds__(1024) void k_scanP(int* __restrict__ priv,
                                                int* __restrict__ offsets) {
    __shared__ int sw[1024];
    const int t = threadIdx.x;
    int tot[8];
    #pragma unroll
    for (int i = 0; i < 8; ++i) {
        const int key = t * 8 + i;
        int run = 0;
        for (int b = 0; b < NFB; ++b) {
            int* p = priv + b * 8192 + key;
            int v = *p; *p = run; run += v;
        }
        tot[i] = run;
    }
    int myTot = 0;
    #pragma unroll
    for (int i = 0; i < 8; ++i) myTot += tot[i];
    sw[t] = myTot;
    __syncthreads();
    for (int off = 1; off < 1024; off <<= 1) {
        int v = (t >= off) ? sw[t - off] : 0;
        __syncthreads();
        sw[t] += v;
        __syncthreads();
    }
    int base = sw[t] - myTot;
    int kb[8];
    #pragma unroll
    for (int i = 0; i < 8; ++i) { kb[i] = base; base += tot[i]; }
    #pragma unroll
    for (int i = 0; i < 8; ++i) {
        const int key = t * 8 + i;
        offsets[key] = kb[i];
        for (int b = 0; b < NFB; ++b) priv[b * 8192 + key] += kb[i];
    }
    if (t == 1023) offsets[8192] = NE;
}

__global__ __launch_bounds__(1024) void k_fillB(const int* __restrict__ smap,
                                                const float* __restrict__ wts,
                                                const int* __restrict__ priv,
                                                const unsigned* __restrict__ hdr,
                                                int4* __restrict__ entries) {
    __shared__ int cur[8192];
    const int b = blockIdx.x;
    const int t = threadIdx.x;
    for (int i = t; i < 8192; i += 1024) cur[i] = priv[b * 8192 + i];
    __syncthreads();
    const int e0 = b * EPB;
    for (int i = 0; i < EPB / 1024; ++i) {      // 36
        const int e = e0 + i * 1024 + t;
        const int n = smap[e];
        const int o = e / 36;                   // e = o*36 + k*4 + p_tap
        const int r = e - o * 36;
        const int k = r >> 2;
        const unsigned h = hdr[(size_t)o * KK + k];
        const int pos = atomicAdd(&cur[n >> 5], 1);
        entries[pos] = make_int4((o << 5) | (n & 31), __float_as_int(wts[e]), (int)h, 0);
    }
}

// ============================================================================
// Gather: block = one 32-n chunk x ALL 512 planes. Wave-per-entry:
// lane l reads the k-sorted run xk[o][start+l] (coalesced) and ds_adds into
// acc[nl][p^nl]. XCD-contiguous chunk swizzle: consecutive chunks co-resident
// per XCD so L2 merges the 128B/plane flush segments into full-line evictions.
// Plain cached stores (NT removed — NT 128B scatter capped writes at 700GB/s).
// ============================================================================
__global__ __launch_bounds__(GTH) void k_gather5(const int* __restrict__ offsets,
                                                 const int4* __restrict__ entries,
                                                 const unsigned* __restrict__ xk,
                                                 float* __restrict__ out) {
    __shared__ float acc[CHUNK * NPLANES];       // 64 KB
    const int bid = blockIdx.x;
    const int c = (bid & 7) * (NCHUNKS / 8) + (bid >> 3);   // XCD-contiguous
    const int tid = threadIdx.x;
    const int lane = tid & 63;
    const int wid = tid >> 6;

    float4* a4 = (float4*)acc;
    for (int i = tid; i < CHUNK * NPLANES / 4; i += GTH) a4[i] = float4{0.f, 0.f, 0.f, 0.f};
    __syncthreads();

    const int j1 = offsets[c + 1];
    int j = offsets[c] + wid;
    int4 e = make_int4(0, 0, 0, 0);
    unsigned u0 = 0;
    bool have = (j < j1);
    if (have) {
        e = entries[j];
        int o = ((unsigned)e.x) >> 5;
        int st = e.z & 0xFFFF;
        int cn = ((unsigned)e.z) >> 16;
        if (lane < cn) u0 = xk[((size_t)o << 9) + st + lane];
    }
    while (have) {
        const int jn = j + NW;
        const bool hn = (jn < j1);
        int4 en = make_int4(0, 0, 0, 0);
        unsigned un = 0;
        if (hn) {
            en = entries[jn];
            int on = ((unsigned)en.x) >> 5;
            int stn = en.z & 0xFFFF;
            int cnn = ((unsigned)en.z) >> 16;
            if (lane < cnn) un = xk[((size_t)on << 9) + stn + lane];
        }
        {
            const int nl = e.x & 31;
            const float w = __int_as_float(e.y);
            const int cn = ((unsigned)e.z) >> 16;
            if (lane < cn) {
                int p = u0 & 511;
                float xv = __int_as_float(u0 & 0xFFFFFE00u);
                atomicAdd(&acc[(nl << 9) + (p ^ nl)], w * xv);
            }
            if (cn > 64) {
                const int o = ((unsigned)e.x) >> 5;
                const int st = e.z & 0xFFFF;
                for (int b = lane + 64; b < cn; b += 64) {
                    unsigned u = xk[((size_t)o << 9) + st + b];
                    int p = u & 511;
                    float xv = __int_as_float(u & 0xFFFFFE00u);
                    atomicAdd(&acc[(nl << 9) + (p ^ nl)], w * xv);
                }
            }
        }
        e = en; u0 = un; j = jn; have = hn;
    }
    __syncthreads();

    // flush: thread -> (p = i>>3, q = i&7), float4 over nl = 4q..4q+3.
    // LDS read banks: (p ^ nl) & 31, 2 lanes/bank worst case (free).
    // Global: 8 lanes cover one 128B plane segment; L2 merges across blocks.
    const int n0 = c << 5;
    for (int i = tid; i < CHUNK * NPLANES / 4; i += GTH) {
        const int p = i >> 3;
        const int nl = (i & 7) << 2;
        float4 v;
        v.x = acc[((nl + 0) << 9) + (p ^ (nl + 0))];
        v.y = acc[((nl + 1) << 9) + (p ^ (nl + 1))];
        v.z = acc[((nl + 2) << 9) + (p ^ (nl + 2))];
        v.w = acc[((nl + 3) << 9) + (p ^ (nl + 3))];
        *(float4*)(out + (size_t)p * N_IN + n0 + nl) = v;
    }
}

// ============================================================================
// Fallback (ws too small): atomic scatter
// ============================================================================
__global__ __launch_bounds__(256) void zero_kernel(float4* __restrict__ out, int n4) {
    int i = blockIdx.x * blockDim.x + threadIdx.x;
    int stride = gridDim.x * blockDim.x;
    const float4 z = {0.f, 0.f, 0.f, 0.f};
    for (; i < n4; i += stride) out[i] = z;
}

__global__ __launch_bounds__(256) void scatter_kernel(
    const float* __restrict__ x, const int* __restrict__ idx_mask,
    const int4* __restrict__ smap, const float4* __restrict__ wts,
    float* __restrict__ out)
{
    const int plane = blockIdx.x >> 8;
    const int o = ((blockIdx.x & 255) << 8) + threadIdx.x;
    const long ibase = (long)plane * N_OUT + o;
    const float xv = x[ibase];
    const int k = idx_mask[ibase];
    const int row = o * KK + k;
    const int4 m = smap[row];
    const float4 w = wts[row];
    float* op = out + (long)plane * N_IN;
    atomicAdd(op + m.x, w.x * xv);
    atomicAdd(op + m.y, w.y * xv);
    atomicAdd(op + m.z, w.z * xv);
    atomicAdd(op + m.w, w.w * xv);
}

// ============================================================================
extern "C" void kernel_launch(void* const* d_in, const int* in_sizes, int n_in,
                              void* d_out, int out_size, void* d_ws, size_t ws_size,
                              hipStream_t stream) {
    const float* x    = (const float*)d_in[0];
    const int*   idx  = (const int*)d_in[1];
    const int*   smap = (const int*)d_in[2];
    const float* wts  = (const float*)d_in[3];
    float* out = (float*)d_out;

    if (ws_size < (size_t)WS_END * 4) {
        zero_kernel<<<4096, 256, 0, stream>>>((float4*)out, out_size / 4);
        scatter_kernel<<<NPLANES * (N_OUT / 256), 256, 0, stream>>>(
            x, idx, (const int4*)smap, (const float4*)wts, out);
        return;
    }

    int* ws = (int*)d_ws;
    int* offsets   = ws + WS_OFFSETS;
    int* priv      = ws + WS_PRIV;
    unsigned* hdr  = (unsigned*)(ws + WS_HDR);
    int4* entries  = (int4*)(ws + WS_ENTR);
    unsigned* xk   = (unsigned*)(ws + WS_XK);

    // 1) k-sorted xk + run headers
    k_xk<<<N_OUT / XKTILE, 256, 0, stream>>>(x, idx, xk, hdr);
    // 2) per-build-block private histograms (LDS, no global atomics)
    k_histA<<<NFB, 1024, 0, stream>>>(smap, priv);
    // 3) two-level exclusive scan -> per-(block,key) bases + bucket offsets
    k_scanP<<<1, 1024, 0, stream>>>(priv, offsets);
    // 4) fill entries at deterministic bases (LDS cursors only)
    k_fillB<<<NFB, 1024, 0, stream>>>(smap, wts, priv, hdr, entries);
    // 5) gather: one block per 32-n chunk, all 512 planes
    k_gather5<<<NCHUNKS, GTH, 0, stream>>>(offsets, entries, xk, out);
}

// Round 8
// 1012.445 us; speedup vs baseline: 1.7931x; 1.7931x over previous
//
#include <hip/hip_runtime.h>

// x:              [B, C, N_OUT]  f32   (512 planes x 65536)
// idx_mask:       [B, C, N_OUT]  i32 in [0, K)
// sample_map:     [N_OUT, K, P]  i32 in [0, N_IN)
// interp_weights: [N_OUT, K, P]  f32
// out:            [B, C, N_IN]   f32
#define BB      8
#define CC      64
#define N_OUT   65536
#define N_IN    262144
#define KK      9
#define PP      4
#define NE      (N_OUT * KK * PP)   // 2,359,296
#define NPLANES 512
#define CHUNK   32                  // n per gather block
#define NCHUNKS (N_IN / CHUNK)      // 8192
#define GTH     512                 // gather threads (8 waves)
#define NW      (GTH / 64)
#define NFB     128                 // fill/hist blocks
#define EPB     (NE / NFB)          // 18432 entries per build block

// ---------------- d_ws layout (int units) ----------------
// offsets [8193+pad]     bucket bases
// tot     [8192]         per-key totals (colscan -> scan8k input)
// priv    [NFB][8192]    per-build-block within-key exclusive prefix
// hdr     [N_OUT*9] u32 = start | (cnt<<16) per (o,k) into xk row
// entries int4[NE]       {(o<<5)|nl, w_bits, start|(cnt<<16), 0}
// xk      u32[N_OUT*512] per o: planes k-sorted, (x_bits & ~511) | plane_id
#define WS_OFFSETS 0
#define WS_TOT     8208
#define WS_PRIV    16400
#define WS_HDR     (16400 + NFB * 8192)           // 1064976
#define WS_ENTR    (1064976 + N_OUT * KK)         // 1654800 (16B aligned)
#define WS_XK      (1654800 + 4 * NE)             // 11091984
#define WS_END     (11091984 + N_OUT * 512)       // 44646416 ints (~170.3 MiB)

// ============================================================================
// k_xk: per o, sort the 512 planes' x by their idx_mask tap k.
//   xk[o][j] (j in k-sorted order) = (x_bits & 0xFFFFFE00) | plane_id (9 bits)
//   hdr[o*9+k] = start | (cnt << 16)
// ============================================================================
#define XKTILE 16
#define XPAD   520
__global__ __launch_bounds__(256) void k_xk(const float* __restrict__ x,
                                            const int*   __restrict__ idx,
                                            unsigned* __restrict__ xk,
                                            unsigned* __restrict__ hdr) {
    __shared__ float xs[XKTILE * XPAD];          // 33.3 KB [oo][p] padded
    __shared__ unsigned char ks[XKTILE * XPAD];  // 8.3 KB
    __shared__ unsigned ot[XKTILE * 512];        // 32 KB out tile
    __shared__ int cnt[XKTILE][12];
    __shared__ int cur[XKTILE][12];
    const int t = threadIdx.x;
    const int obase = blockIdx.x * XKTILE;

    for (int i = t; i < XKTILE * 12; i += 256) cnt[i / 12][i % 12] = 0;

    for (int i = t; i < 512 * (XKTILE / 4); i += 256) {   // 2048
        int p = i >> 2, q = i & 3;
        const size_t g = (size_t)p * N_OUT + obase + 4 * q;
        float4 xv = *(const float4*)(x + g);
        int4   kv = *(const int4*)(idx + g);
        int b = (4 * q) * XPAD + p;
        xs[b] = xv.x; xs[b + XPAD] = xv.y; xs[b + 2 * XPAD] = xv.z; xs[b + 3 * XPAD] = xv.w;
        ks[b] = (unsigned char)kv.x; ks[b + XPAD] = (unsigned char)kv.y;
        ks[b + 2 * XPAD] = (unsigned char)kv.z; ks[b + 3 * XPAD] = (unsigned char)kv.w;
    }
    __syncthreads();
    for (int i = t; i < XKTILE * 512; i += 256) {
        int oo = i >> 9, p = i & 511;
        atomicAdd(&cnt[oo][ks[oo * XPAD + p]], 1);
    }
    __syncthreads();
    if (t < XKTILE) {
        int s = 0;
        for (int k = 0; k < KK; ++k) {
            int c = cnt[t][k];
            cur[t][k] = s;
            hdr[(size_t)(obase + t) * KK + k] = (unsigned)(s | (c << 16));
            s += c;
        }
    }
    __syncthreads();
    for (int i = t; i < XKTILE * 512; i += 256) {
        int oo = i >> 9, p = i & 511;
        int k = ks[oo * XPAD + p];
        int pos = atomicAdd(&cur[oo][k], 1);
        unsigned xb = __float_as_uint(xs[oo * XPAD + p]);
        ot[(oo << 9) + pos] = (xb & 0xFFFFFE00u) | (unsigned)p;
    }
    __syncthreads();
    for (int i = t; i < XKTILE * 128; i += 256) {
        int oo = i >> 7, c4 = i & 127;
        ((int4*)(xk + (((size_t)(obase + oo)) << 9)))[c4] = ((const int4*)(ot + (oo << 9)))[c4];
    }
}

// ============================================================================
// Build phase: deterministic counting sort, no global atomics.
// ============================================================================
__global__ __launch_bounds__(1024) void k_histA(const int* __restrict__ smap,
                                                int* __restrict__ priv) {
    __shared__ int h[8192];
    const int b = blockIdx.x;
    const int t = threadIdx.x;
    for (int i = t; i < 8192; i += 1024) h[i] = 0;
    __syncthreads();
    const int e0 = b * EPB;
    #pragma unroll 4
    for (int i = 0; i < EPB / 1024; ++i)
        atomicAdd(&h[smap[e0 + i * 1024 + t] >> 5], 1);
    __syncthreads();
    for (int i = t; i < 8192; i += 1024) priv[b * 8192 + i] = h[i];
}

// 8192 parallel column scans (one key per thread): priv[b][key] becomes the
// within-key exclusive prefix over build blocks; tot[key] = column total.
__global__ __launch_bounds__(1024) void k_colscan(int* __restrict__ priv,
                                                  int* __restrict__ tot) {
    const int key = blockIdx.x * 1024 + threadIdx.x;
    int run = 0;
    for (int b = 0; b < NFB; ++b) {
        int* p = priv + b * 8192 + key;
        int v = *p; *p = run; run += v;
    }
    tot[key] = run;
}

// single-block exclusive scan over 8192 totals -> bucket offsets
__global__ __launch_bounds__(1024) void k_scan8k(const int* __restrict__ counts,
                                                 int* __restrict__ offsets) {
    __shared__ int sw[1024];
    const int t = threadIdx.x;
    int4 a = ((const int4*)counts)[2 * t];
    int4 b = ((const int4*)counts)[2 * t + 1];
    int s = a.x + a.y + a.z + a.w + b.x + b.y + b.z + b.w;
    sw[t] = s;
    __syncthreads();
    for (int off = 1; off < 1024; off <<= 1) {
        int v = (t >= off) ? sw[t - off] : 0;
        __syncthreads();
        sw[t] += v;
        __syncthreads();
    }
    int run = sw[t] - s;
    int vals[8] = {a.x, a.y, a.z, a.w, b.x, b.y, b.z, b.w};
    int o[8];
    #pragma unroll
    for (int q = 0; q < 8; ++q) { o[q] = run; run += vals[q]; }
    ((int4*)offsets)[2 * t]     = make_int4(o[0], o[1], o[2], o[3]);
    ((int4*)offsets)[2 * t + 1] = make_int4(o[4], o[5], o[6], o[7]);
    if (t == 1023) offsets[8192] = NE;
}

__global__ __launch_bounds__(1024) void k_fillB(const int* __restrict__ smap,
                                                const float* __restrict__ wts,
                                                const int* __restrict__ priv,
                                                const int* __restrict__ offsets,
                                                const unsigned* __restrict__ hdr,
                                                int4* __restrict__ entries) {
    __shared__ int cur[8192];
    const int b = blockIdx.x;
    const int t = threadIdx.x;
    for (int i = t; i < 8192; i += 1024) cur[i] = offsets[i] + priv[b * 8192 + i];
    __syncthreads();
    const int e0 = b * EPB;
    for (int i = 0; i < EPB / 1024; ++i) {      // 18
        const int e = e0 + i * 1024 + t;
        const int n = smap[e];
        const int o = e / 36;                   // e = o*36 + k*4 + p_tap
        const int r = e - o * 36;
        const int k = r >> 2;
        const unsigned h = hdr[(size_t)o * KK + k];
        const int pos = atomicAdd(&cur[n >> 5], 1);
        entries[pos] = make_int4((o << 5) | (n & 31), __float_as_int(wts[e]), (int)h, 0);
    }
}

// ============================================================================
// Gather: block = one 32-n chunk x ALL 512 planes. Wave-per-entry:
// lane l reads the k-sorted run xk[o][start+l] (coalesced) and ds_adds into
// acc[nl][p^nl]. XCD-contiguous chunk swizzle: consecutive chunks co-resident
// per XCD so L2 merges the 128B/plane flush segments into full-line evictions.
// ============================================================================
__global__ __launch_bounds__(GTH) void k_gather5(const int* __restrict__ offsets,
                                                 const int4* __restrict__ entries,
                                                 const unsigned* __restrict__ xk,
                                                 float* __restrict__ out) {
    __shared__ float acc[CHUNK * NPLANES];       // 64 KB
    const int bid = blockIdx.x;
    const int c = (bid & 7) * (NCHUNKS / 8) + (bid >> 3);   // XCD-contiguous
    const int tid = threadIdx.x;
    const int lane = tid & 63;
    const int wid = tid >> 6;

    float4* a4 = (float4*)acc;
    for (int i = tid; i < CHUNK * NPLANES / 4; i += GTH) a4[i] = float4{0.f, 0.f, 0.f, 0.f};
    __syncthreads();

    const int j1 = offsets[c + 1];
    int j = offsets[c] + wid;
    int4 e = make_int4(0, 0, 0, 0);
    unsigned u0 = 0;
    bool have = (j < j1);
    if (have) {
        e = entries[j];
        int o = ((unsigned)e.x) >> 5;
        int st = e.z & 0xFFFF;
        int cn = ((unsigned)e.z) >> 16;
        if (lane < cn) u0 = xk[((size_t)o << 9) + st + lane];
    }
    while (have) {
        const int jn = j + NW;
        const bool hn = (jn < j1);
        int4 en = make_int4(0, 0, 0, 0);
        unsigned un = 0;
        if (hn) {
            en = entries[jn];
            int on = ((unsigned)en.x) >> 5;
            int stn = en.z & 0xFFFF;
            int cnn = ((unsigned)en.z) >> 16;
            if (lane < cnn) un = xk[((size_t)on << 9) + stn + lane];
        }
        {
            const int nl = e.x & 31;
            const float w = __int_as_float(e.y);
            const int cn = ((unsigned)e.z) >> 16;
            if (lane < cn) {
                int p = u0 & 511;
                float xv = __int_as_float(u0 & 0xFFFFFE00u);
                atomicAdd(&acc[(nl << 9) + (p ^ nl)], w * xv);
            }
            if (cn > 64) {
                const int o = ((unsigned)e.x) >> 5;
                const int st = e.z & 0xFFFF;
                for (int b = lane + 64; b < cn; b += 64) {
                    unsigned u = xk[((size_t)o << 9) + st + b];
                    int p = u & 511;
                    float xv = __int_as_float(u & 0xFFFFFE00u);
                    atomicAdd(&acc[(nl << 9) + (p ^ nl)], w * xv);
                }
            }
        }
        e = en; u0 = un; j = jn; have = hn;
    }
    __syncthreads();

    // flush: thread -> (p = i>>3, q = i&7), float4 over nl = 4q..4q+3.
    const int n0 = c << 5;
    for (int i = tid; i < CHUNK * NPLANES / 4; i += GTH) {
        const int p = i >> 3;
        const int nl = (i & 7) << 2;
        float4 v;
        v.x = acc[((nl + 0) << 9) + (p ^ (nl + 0))];
        v.y = acc[((nl + 1) << 9) + (p ^ (nl + 1))];
        v.z = acc[((nl + 2) << 9) + (p ^ (nl + 2))];
        v.w = acc[((nl + 3) << 9) + (p ^ (nl + 3))];
        *(float4*)(out + (size_t)p * N_IN + n0 + nl) = v;
    }
}

// ============================================================================
// Fallback (ws too small): atomic scatter
// ============================================================================
__global__ __launch_bounds__(256) void zero_kernel(float4* __restrict__ out, int n4) {
    int i = blockIdx.x * blockDim.x + threadIdx.x;
    int stride = gridDim.x * blockDim.x;
    const float4 z = {0.f, 0.f, 0.f, 0.f};
    for (; i < n4; i += stride) out[i] = z;
}

__global__ __launch_bounds__(256) void scatter_kernel(
    const float* __restrict__ x, const int* __restrict__ idx_mask,
    const int4* __restrict__ smap, const float4* __restrict__ wts,
    float* __restrict__ out)
{
    const int plane = blockIdx.x >> 8;
    const int o = ((blockIdx.x & 255) << 8) + threadIdx.x;
    const long ibase = (long)plane * N_OUT + o;
    const float xv = x[ibase];
    const int k = idx_mask[ibase];
    const int row = o * KK + k;
    const int4 m = smap[row];
    const float4 w = wts[row];
    float* op = out + (long)plane * N_IN;
    atomicAdd(op + m.x, w.x * xv);
    atomicAdd(op + m.y, w.y * xv);
    atomicAdd(op + m.z, w.z * xv);
    atomicAdd(op + m.w, w.w * xv);
}

// ============================================================================
extern "C" void kernel_launch(void* const* d_in, const int* in_sizes, int n_in,
                              void* d_out, int out_size, void* d_ws, size_t ws_size,
                              hipStream_t stream) {
    const float* x    = (const float*)d_in[0];
    const int*   idx  = (const int*)d_in[1];
    const int*   smap = (const int*)d_in[2];
    const float* wts  = (const float*)d_in[3];
    float* out = (float*)d_out;

    if (ws_size < (size_t)WS_END * 4) {
        zero_kernel<<<4096, 256, 0, stream>>>((float4*)out, out_size / 4);
        scatter_kernel<<<NPLANES * (N_OUT / 256), 256, 0, stream>>>(
            x, idx, (const int4*)smap, (const float4*)wts, out);
        return;
    }

    int* ws = (int*)d_ws;
    int* offsets   = ws + WS_OFFSETS;
    int* tot       = ws + WS_TOT;
    int* priv      = ws + WS_PRIV;
    unsigned* hdr  = (unsigned*)(ws + WS_HDR);
    int4* entries  = (int4*)(ws + WS_ENTR);
    unsigned* xk   = (unsigned*)(ws + WS_XK);

    // 1) k-sorted xk + run headers
    k_xk<<<N_OUT / XKTILE, 256, 0, stream>>>(x, idx, xk, hdr);
    // 2) per-build-block private histograms (LDS, no global atomics)
    k_histA<<<NFB, 1024, 0, stream>>>(smap, priv);
    // 3a) 8192 parallel column scans over build blocks
    k_colscan<<<8, 1024, 0, stream>>>(priv, tot);
    // 3b) exclusive scan of key totals -> bucket offsets
    k_scan8k<<<1, 1024, 0, stream>>>(tot, offsets);
    // 4) fill entries at deterministic bases (LDS cursors only)
    k_fillB<<<NFB, 1024, 0, stream>>>(smap, wts, priv, offsets, hdr, entries);
    // 5) gather: one block per 32-n chunk, all 512 planes
    k_gather5<<<NCHUNKS, GTH, 0, stream>>>(offsets, entries, xk, out);
}

// Round 9
// 965.645 us; speedup vs baseline: 1.8800x; 1.0485x over previous
//
#include <hip/hip_runtime.h>

// x:              [B, C, N_OUT]  f32   (512 planes x 65536)
// idx_mask:       [B, C, N_OUT]  i32 in [0, K)
// sample_map:     [N_OUT, K, P]  i32 in [0, N_IN)
// interp_weights: [N_OUT, K, P]  f32
// out:            [B, C, N_IN]   f32
#define BB      8
#define CC      64
#define N_OUT   65536
#define N_IN    262144
#define KK      9
#define PP      4
#define NE      (N_OUT * KK * PP)   // 2,359,296
#define NPLANES 512
#define CHUNK   16                  // n per gather block (32 KB acc -> 4 blocks/CU)
#define NCHUNKS (N_IN / CHUNK)      // 16384
#define NKEY    NCHUNKS
#define GTH     512                 // gather threads (8 waves)
#define NW      (GTH / 64)
#define NFB     128                 // fill/hist blocks
#define EPB     (NE / NFB)          // 18432 entries per build block

// ---------------- d_ws layout (int units) ----------------
#define WS_OFFSETS 0
#define WS_TOT     16400
#define WS_PRIV    32784
#define WS_HDR     (32784 + NFB * NKEY)            // 2129936
#define WS_ENTR    (2129936 + N_OUT * KK)          // 2719760 (16B aligned)
#define WS_XK      (2719760 + 4 * NE)              // 12156944
#define WS_END     (12156944 + N_OUT * 512)        // 45711376 ints (~174.4 MiB)

// ============================================================================
// k_xk: per o, sort the 512 planes' x by their idx_mask tap k.
//   xk[o][j] (k-sorted order) = (x_bits & 0xFFFFFE00) | plane_id (9 bits)
//   hdr[o*9+k] = start | (cnt << 16)
// ============================================================================
#define XKTILE 16
#define XPAD   520
__global__ __launch_bounds__(256) void k_xk(const float* __restrict__ x,
                                            const int*   __restrict__ idx,
                                            unsigned* __restrict__ xk,
                                            unsigned* __restrict__ hdr) {
    __shared__ float xs[XKTILE * XPAD];
    __shared__ unsigned char ks[XKTILE * XPAD];
    __shared__ unsigned ot[XKTILE * 512];
    __shared__ int cnt[XKTILE][12];
    __shared__ int cur[XKTILE][12];
    const int t = threadIdx.x;
    const int obase = blockIdx.x * XKTILE;

    for (int i = t; i < XKTILE * 12; i += 256) cnt[i / 12][i % 12] = 0;

    for (int i = t; i < 512 * (XKTILE / 4); i += 256) {
        int p = i >> 2, q = i & 3;
        const size_t g = (size_t)p * N_OUT + obase + 4 * q;
        float4 xv = *(const float4*)(x + g);
        int4   kv = *(const int4*)(idx + g);
        int b = (4 * q) * XPAD + p;
        xs[b] = xv.x; xs[b + XPAD] = xv.y; xs[b + 2 * XPAD] = xv.z; xs[b + 3 * XPAD] = xv.w;
        ks[b] = (unsigned char)kv.x; ks[b + XPAD] = (unsigned char)kv.y;
        ks[b + 2 * XPAD] = (unsigned char)kv.z; ks[b + 3 * XPAD] = (unsigned char)kv.w;
    }
    __syncthreads();
    for (int i = t; i < XKTILE * 512; i += 256) {
        int oo = i >> 9, p = i & 511;
        atomicAdd(&cnt[oo][ks[oo * XPAD + p]], 1);
    }
    __syncthreads();
    if (t < XKTILE) {
        int s = 0;
        for (int k = 0; k < KK; ++k) {
            int c = cnt[t][k];
            cur[t][k] = s;
            hdr[(size_t)(obase + t) * KK + k] = (unsigned)(s | (c << 16));
            s += c;
        }
    }
    __syncthreads();
    for (int i = t; i < XKTILE * 512; i += 256) {
        int oo = i >> 9, p = i & 511;
        int k = ks[oo * XPAD + p];
        int pos = atomicAdd(&cur[oo][k], 1);
        unsigned xb = __float_as_uint(xs[oo * XPAD + p]);
        ot[(oo << 9) + pos] = (xb & 0xFFFFFE00u) | (unsigned)p;
    }
    __syncthreads();
    for (int i = t; i < XKTILE * 128; i += 256) {
        int oo = i >> 7, c4 = i & 127;
        ((int4*)(xk + (((size_t)(obase + oo)) << 9)))[c4] = ((const int4*)(ot + (oo << 9)))[c4];
    }
}

// ============================================================================
// Build: deterministic counting sort over 16384 chunk keys, no global atomics.
// ============================================================================
__global__ __launch_bounds__(1024) void k_histA(const int* __restrict__ smap,
                                                int* __restrict__ priv) {
    __shared__ int h[NKEY];
    const int b = blockIdx.x;
    const int t = threadIdx.x;
    for (int i = t; i < NKEY; i += 1024) h[i] = 0;
    __syncthreads();
    const int e0 = b * EPB;
    #pragma unroll 2
    for (int i = 0; i < EPB / 1024; ++i)
        atomicAdd(&h[smap[e0 + i * 1024 + t] >> 4], 1);
    __syncthreads();
    for (int i = t; i < NKEY; i += 1024) priv[b * NKEY + i] = h[i];
}

// 16384 parallel column scans (one key per thread)
__global__ __launch_bounds__(1024) void k_colscan(int* __restrict__ priv,
                                                  int* __restrict__ tot) {
    const int key = blockIdx.x * 1024 + threadIdx.x;
    int run = 0;
    for (int b = 0; b < NFB; ++b) {
        int* p = priv + b * NKEY + key;
        int v = *p; *p = run; run += v;
    }
    tot[key] = run;
}

// single-block exclusive scan over 16384 totals -> bucket offsets
__global__ __launch_bounds__(1024) void k_scan16k(const int* __restrict__ tot,
                                                  int* __restrict__ offsets) {
    __shared__ int sw[1024];
    const int t = threadIdx.x;
    int4 q0 = ((const int4*)tot)[4 * t + 0];
    int4 q1 = ((const int4*)tot)[4 * t + 1];
    int4 q2 = ((const int4*)tot)[4 * t + 2];
    int4 q3 = ((const int4*)tot)[4 * t + 3];
    int vals[16] = {q0.x, q0.y, q0.z, q0.w, q1.x, q1.y, q1.z, q1.w,
                    q2.x, q2.y, q2.z, q2.w, q3.x, q3.y, q3.z, q3.w};
    int s = 0;
    #pragma unroll
    for (int i = 0; i < 16; ++i) s += vals[i];
    sw[t] = s;
    __syncthreads();
    for (int off = 1; off < 1024; off <<= 1) {
        int v = (t >= off) ? sw[t - off] : 0;
        __syncthreads();
        sw[t] += v;
        __syncthreads();
    }
    int run = sw[t] - s;
    int o[16];
    #pragma unroll
    for (int i = 0; i < 16; ++i) { o[i] = run; run += vals[i]; }
    ((int4*)offsets)[4 * t + 0] = make_int4(o[0], o[1], o[2], o[3]);
    ((int4*)offsets)[4 * t + 1] = make_int4(o[4], o[5], o[6], o[7]);
    ((int4*)offsets)[4 * t + 2] = make_int4(o[8], o[9], o[10], o[11]);
    ((int4*)offsets)[4 * t + 3] = make_int4(o[12], o[13], o[14], o[15]);
    if (t == 1023) offsets[NKEY] = NE;
}

// fill entries at deterministic bases; entry = {(o<<4)|nl, w, start|(cnt<<16), 0}
__global__ __launch_bounds__(1024) void k_fillB(const int* __restrict__ smap,
                                                const float* __restrict__ wts,
                                                const int* __restrict__ priv,
                                                const int* __restrict__ offsets,
                                                const unsigned* __restrict__ hdr,
                                                int4* __restrict__ entries) {
    __shared__ int cur[NKEY];
    const int b = blockIdx.x;
    const int t = threadIdx.x;
    for (int i = t; i < NKEY; i += 1024) cur[i] = offsets[i] + priv[b * NKEY + i];
    __syncthreads();
    const int e0 = b * EPB;
    for (int i = 0; i < EPB / 1024; ++i) {      // 18
        const int e = e0 + i * 1024 + t;
        const int n = smap[e];
        const int o = e / 36;                   // e = o*36 + k*4 + p_tap
        const int r = e - o * 36;
        const int k = r >> 2;
        const unsigned h = hdr[(size_t)o * KK + k];
        const int pos = atomicAdd(&cur[n >> 4], 1);
        entries[pos] = make_int4((o << 4) | (n & 15), __float_as_int(wts[e]), (int)h, 0);
    }
}

// ============================================================================
// Gather v6: block = one 16-n chunk x ALL 512 planes (32 KB acc, 4 blocks/CU).
// Stage-split unroll-2 pipeline: C(entry in flight) -> B(issue xk) -> A(compute).
// 2 xk loads in flight per wave; tail half-run (cn in (64,128]) prefetched too.
// LDS swizzle p ^ (nl<<1): ds_add and flush both <=2-way on banks.
// ============================================================================
#define SWZ(p, nl) ((p) ^ ((nl) << 1))
__global__ __launch_bounds__(GTH, 8) void k_gather6(const int* __restrict__ offsets,
                                                    const int4* __restrict__ entries,
                                                    const unsigned* __restrict__ xk,
                                                    float* __restrict__ out) {
    __shared__ float acc[CHUNK * NPLANES];       // 32 KB
    const int bid = blockIdx.x;
    const int c = (bid & 7) * (NCHUNKS / 8) + (bid >> 3);   // XCD-contiguous
    const int tid = threadIdx.x;
    const int lane = tid & 63;
    const int wid = tid >> 6;

    float4* a4 = (float4*)acc;
    for (int i = tid; i < CHUNK * NPLANES / 4; i += GTH) a4[i] = float4{0.f, 0.f, 0.f, 0.f};
    __syncthreads();

    const int j1 = offsets[c + 1];
    int jA = offsets[c] + wid;

    int4 eA0 = {0,0,0,0}, eA1 = {0,0,0,0};
    if (jA < j1)      eA0 = entries[jA];
    if (jA + NW < j1) eA1 = entries[jA + NW];
    unsigned xA0 = 0, xA1 = 0, xA0b = 0, xA1b = 0;
    if (jA < j1) {
        int o = ((unsigned)eA0.x) >> 4, st = eA0.z & 0xFFFF, cn = ((unsigned)eA0.z) >> 16;
        const unsigned* r = xk + ((size_t)o << 9) + st;
        if (lane < cn) xA0 = r[lane];
        if (cn > 64 && lane + 64 < cn) xA0b = r[lane + 64];
    }
    if (jA + NW < j1) {
        int o = ((unsigned)eA1.x) >> 4, st = eA1.z & 0xFFFF, cn = ((unsigned)eA1.z) >> 16;
        const unsigned* r = xk + ((size_t)o << 9) + st;
        if (lane < cn) xA1 = r[lane];
        if (cn > 64 && lane + 64 < cn) xA1b = r[lane + 64];
    }
    int jB = jA + 2 * NW;
    int4 eB0 = {0,0,0,0}, eB1 = {0,0,0,0};
    if (jB < j1)      eB0 = entries[jB];
    if (jB + NW < j1) eB1 = entries[jB + NW];

    while (jA < j1) {
        // issue xk for B slots (entries already arrived)
        unsigned xB0 = 0, xB1 = 0, xB0b = 0, xB1b = 0;
        if (jB < j1) {
            int o = ((unsigned)eB0.x) >> 4, st = eB0.z & 0xFFFF, cn = ((unsigned)eB0.z) >> 16;
            const unsigned* r = xk + ((size_t)o << 9) + st;
            if (lane < cn) xB0 = r[lane];
            if (cn > 64 && lane + 64 < cn) xB0b = r[lane + 64];
        }
        if (jB + NW < j1) {
            int o = ((unsigned)eB1.x) >> 4, st = eB1.z & 0xFFFF, cn = ((unsigned)eB1.z) >> 16;
            const unsigned* r = xk + ((size_t)o << 9) + st;
            if (lane < cn) xB1 = r[lane];
            if (cn > 64 && lane + 64 < cn) xB1b = r[lane + 64];
        }
        // prefetch C entries
        const int jC = jB + 2 * NW;
        int4 eC0 = {0,0,0,0}, eC1 = {0,0,0,0};
        if (jC < j1)      eC0 = entries[jC];
        if (jC + NW < j1) eC1 = entries[jC + NW];

        // compute A slots
        if (jA < j1) {
            const int nl = eA0.x & 15, cn = ((unsigned)eA0.z) >> 16;
            const float w = __int_as_float(eA0.y);
            if (lane < cn) {
                int p = xA0 & 511;
                atomicAdd(&acc[(nl << 9) + SWZ(p, nl)], w * __int_as_float(xA0 & 0xFFFFFE00u));
            }
            if (cn > 64 && lane + 64 < cn) {
                int p = xA0b & 511;
                atomicAdd(&acc[(nl << 9) + SWZ(p, nl)], w * __int_as_float(xA0b & 0xFFFFFE00u));
            }
            if (cn > 128) {                      // essentially never (Binom(512,1/9))
                const int o = ((unsigned)eA0.x) >> 4, st = eA0.z & 0xFFFF;
                for (int b = lane + 128; b < cn; b += 64) {
                    unsigned u = xk[((size_t)o << 9) + st + b];
                    int p = u & 511;
                    atomicAdd(&acc[(nl << 9) + SWZ(p, nl)], w * __int_as_float(u & 0xFFFFFE00u));
                }
            }
        }
        if (jA + NW < j1) {
            const int nl = eA1.x & 15, cn = ((unsigned)eA1.z) >> 16;
            const float w = __int_as_float(eA1.y);
            if (lane < cn) {
                int p = xA1 & 511;
                atomicAdd(&acc[(nl << 9) + SWZ(p, nl)], w * __int_as_float(xA1 & 0xFFFFFE00u));
            }
            if (cn > 64 && lane + 64 < cn) {
                int p = xA1b & 511;
                atomicAdd(&acc[(nl << 9) + SWZ(p, nl)], w * __int_as_float(xA1b & 0xFFFFFE00u));
            }
            if (cn > 128) {
                const int o = ((unsigned)eA1.x) >> 4, st = eA1.z & 0xFFFF;
                for (int b = lane + 128; b < cn; b += 64) {
                    unsigned u = xk[((size_t)o << 9) + st + b];
                    int p = u & 511;
                    atomicAdd(&acc[(nl << 9) + SWZ(p, nl)], w * __int_as_float(u & 0xFFFFFE00u));
                }
            }
        }
        // rotate
        eA0 = eB0; eA1 = eB1;
        xA0 = xB0; xA1 = xB1; xA0b = xB0b; xA1b = xB1b;
        jA = jB;
        eB0 = eC0; eB1 = eC1; jB = jC;
    }
    __syncthreads();

    // flush: i>>2 = p, (i&3)<<2 = nl quad; 4 lanes cover 64B of one plane row.
    const int n0 = c << 4;
    for (int i = tid; i < CHUNK * NPLANES / 4; i += GTH) {
        const int p = i >> 2;
        const int nl = (i & 3) << 2;
        float4 v;
        v.x = acc[((nl + 0) << 9) + SWZ(p, nl + 0)];
        v.y = acc[((nl + 1) << 9) + SWZ(p, nl + 1)];
        v.z = acc[((nl + 2) << 9) + SWZ(p, nl + 2)];
        v.w = acc[((nl + 3) << 9) + SWZ(p, nl + 3)];
        *(float4*)(out + (size_t)p * N_IN + n0 + nl) = v;
    }
}

// ============================================================================
// Fallback (ws too small): atomic scatter
// ============================================================================
__global__ __launch_bounds__(256) void zero_kernel(float4* __restrict__ out, int n4) {
    int i = blockIdx.x * blockDim.x + threadIdx.x;
    int stride = gridDim.x * blockDim.x;
    const float4 z = {0.f, 0.f, 0.f, 0.f};
    for (; i < n4; i += stride) out[i] = z;
}

__global__ __launch_bounds__(256) void scatter_kernel(
    const float* __restrict__ x, const int* __restrict__ idx_mask,
    const int4* __restrict__ smap, const float4* __restrict__ wts,
    float* __restrict__ out)
{
    const int plane = blockIdx.x >> 8;
    const int o = ((blockIdx.x & 255) << 8) + threadIdx.x;
    const long ibase = (long)plane * N_OUT + o;
    const float xv = x[ibase];
    const int k = idx_mask[ibase];
    const int row = o * KK + k;
    const int4 m = smap[row];
    const float4 w = wts[row];
    float* op = out + (long)plane * N_IN;
    atomicAdd(op + m.x, w.x * xv);
    atomicAdd(op + m.y, w.y * xv);
    atomicAdd(op + m.z, w.z * xv);
    atomicAdd(op + m.w, w.w * xv);
}

// ============================================================================
extern "C" void kernel_launch(void* const* d_in, const int* in_sizes, int n_in,
                              void* d_out, int out_size, void* d_ws, size_t ws_size,
                              hipStream_t stream) {
    const float* x    = (const float*)d_in[0];
    const int*   idx  = (const int*)d_in[1];
    const int*   smap = (const int*)d_in[2];
    const float* wts  = (const float*)d_in[3];
    float* out = (float*)d_out;

    if (ws_size < (size_t)WS_END * 4) {
        zero_kernel<<<4096, 256, 0, stream>>>((float4*)out, out_size / 4);
        scatter_kernel<<<NPLANES * (N_OUT / 256), 256, 0, stream>>>(
            x, idx, (const int4*)smap, (const float4*)wts, out);
        return;
    }

    int* ws = (int*)d_ws;
    int* offsets   = ws + WS_OFFSETS;
    int* tot       = ws + WS_TOT;
    int* priv      = ws + WS_PRIV;
    unsigned* hdr  = (unsigned*)(ws + WS_HDR);
    int4* entries  = (int4*)(ws + WS_ENTR);
    unsigned* xk   = (unsigned*)(ws + WS_XK);

    // 1) k-sorted xk + run headers
    k_xk<<<N_OUT / XKTILE, 256, 0, stream>>>(x, idx, xk, hdr);
    // 2) per-build-block private histograms
    k_histA<<<NFB, 1024, 0, stream>>>(smap, priv);
    // 3a) 16384 parallel column scans
    k_colscan<<<16, 1024, 0, stream>>>(priv, tot);
    // 3b) exclusive scan of key totals -> bucket offsets
    k_scan16k<<<1, 1024, 0, stream>>>(tot, offsets);
    // 4) fill entries at deterministic bases
    k_fillB<<<NFB, 1024, 0, stream>>>(smap, wts, priv, offsets, hdr, entries);
    // 5) gather: one block per 16-n chunk, all 512 planes
    k_gather6<<<NCHUNKS, GTH, 0, stream>>>(offsets, entries, xk, out);
}